// Round 28
// baseline (92.790 us; speedup 1.0000x reference)
//
#include <hip/hip_runtime.h>

typedef short bf16x8 __attribute__((ext_vector_type(8)));
typedef float f32x4 __attribute__((ext_vector_type(4)));
typedef float f32x16 __attribute__((ext_vector_type(16)));
typedef unsigned u32x4v __attribute__((ext_vector_type(4)));

#define T_SEQ 4096
#define CDIM  1024
#define HD    64
#define NROWS 16384  // B*T

__device__ inline float exp2fast(float x) {
  return __builtin_amdgcn_exp2f(x);   // v_exp_f32: D = 2^S0
}

__device__ inline unsigned short f2bf(float f) {
  unsigned u = __builtin_bit_cast(unsigned, f);
  u = (u + 0x7fffu + ((u >> 16) & 1u)) >> 16;
  return (unsigned short)u;
}
__device__ inline unsigned cvt_pk_bf16(float lo, float hi) {
  unsigned r;
  asm("v_cvt_pk_bf16_f32 %0, %1, %2" : "=v"(r) : "v"(lo), "v"(hi));
  return r;
}
__device__ inline float bf2f(unsigned short u) {
  unsigned v = (unsigned)u << 16;
  return __builtin_bit_cast(float, v);
}
// async global->LDS, 16B per lane; LDS dest = wave-uniform base + lane*16
__device__ inline void gload_lds16(const unsigned short* g, unsigned char* l) {
  __builtin_amdgcn_global_load_lds(
      (const __attribute__((address_space(1))) unsigned int*)(const void*)g,
      (__attribute__((address_space(3))) unsigned int*)(void*)l, 16, 0, 0);
}

// ---------------- W prep (LDS transpose): Wt[n][k] bf16 ----------------
__global__ __launch_bounds__(256) void prep_w(
    const float* __restrict__ Wk, const float* __restrict__ Wv,
    unsigned short* __restrict__ Wt) {
  __shared__ float tile[64][68];
  const int t = threadIdx.x;
  const int mat = blockIdx.x & 1;
  const int k0 = (blockIdx.x >> 1) * 64;
  const float* W = mat ? Wv : Wk;
  #pragma unroll
  for (int pp = 0; pp < 4; ++pp) {
    int idx = t + 256 * pp, row = idx >> 4, c4 = idx & 15;
    float4 v = *(const float4*)&W[(size_t)(k0 + row) * HD + c4 * 4];
    *(float4*)&tile[row][c4 * 4] = v;
  }
  __syncthreads();
  #pragma unroll
  for (int j = 0; j < 2; ++j) {
    int n = t & 63, j8 = (t >> 6) + 4 * j;
    unsigned ow[4];
    #pragma unroll
    for (int w = 0; w < 4; ++w)
      ow[w] = cvt_pk_bf16(tile[j8 * 8 + 2 * w][n], tile[j8 * 8 + 2 * w + 1][n]);
    u32x4v ov = {ow[0], ow[1], ow[2], ow[3]};
    *(u32x4v*)&Wt[(size_t)(mat * 64 + n) * CDIM + k0 + j8 * 8] = ov;
  }
}

// ---------------- projection GEMM: [K|V] = x @ Wt^T, bf16 MFMA ----------------
// (byte-identical to rounds 24-26 — verified)
__global__ __launch_bounds__(256) void proj_mfma(
    const float* __restrict__ x, const unsigned short* __restrict__ Wt,
    unsigned short* __restrict__ Kb, unsigned short* __restrict__ Vb) {
  __shared__ __align__(16) unsigned char xsb[16384];
  __shared__ __align__(16) unsigned char wsb[65536];
  const int tid = threadIdx.x;
  const int lane = tid & 63, wave = tid >> 6;
  const int wm = wave & 1, wn = wave >> 1;
  const int lg = lane >> 4, lc = lane & 15;
  const int row0 = blockIdx.x * 64;

  float4 xreg[8];
  auto load_x = [&](int kk) {
    #pragma unroll
    for (int p = 0; p < 8; ++p) {
      int idx = tid + 256 * p, r = idx >> 5, c4 = idx & 31;
      xreg[p] = *(const float4*)&x[(size_t)(row0 + r) * CDIM + kk + c4 * 4];
    }
  };
  auto write_x = [&]() {
    #pragma unroll
    for (int p = 0; p < 8; ++p) {
      int idx = tid + 256 * p, r = idx >> 5, c4 = idx & 31;
      uint2 v;
      v.x = cvt_pk_bf16(xreg[p].x, xreg[p].y);
      v.y = cvt_pk_bf16(xreg[p].z, xreg[p].w);
      int byt = (r * 256 + c4 * 8) ^ ((r & 7) << 4);
      *(uint2*)(xsb + byt) = v;
    }
  };
  auto gload_W = [&](int kk, int buf) {
    unsigned char* wb = wsb + buf * 32768;
    #pragma unroll
    for (int p = 0; p < 8; ++p) {
      int ci = p * 256 + tid;
      int r = ci >> 4;
      int c8 = (ci & 15) ^ (r & 7);
      gload_lds16(&Wt[(size_t)r * CDIM + kk + c8 * 8],
                  wb + (p * 256 + wave * 64) * 16);
    }
  };

  f32x4 acc[2][4];
  #pragma unroll
  for (int mf = 0; mf < 2; ++mf)
    #pragma unroll
    for (int nf = 0; nf < 4; ++nf) acc[mf][nf] = (f32x4){0.f, 0.f, 0.f, 0.f};

  gload_W(0, 0);
  load_x(0);
  for (int kk = 0; kk < CDIM; kk += 128) {
    const int cur = (kk >> 7) & 1;
    __syncthreads();
    write_x();
    __syncthreads();
    if (kk + 128 < CDIM) { gload_W(kk + 128, cur ^ 1); load_x(kk + 128); }
    const unsigned char* wb = wsb + cur * 32768;
    #pragma unroll
    for (int dd = 0; dd < 4; ++dd) {
      bf16x8 a[2], bfr[4];
      #pragma unroll
      for (int mf = 0; mf < 2; ++mf) {
        int r = wm * 32 + mf * 16 + lc;
        int sw = (r & 7) << 4;
        a[mf] = *(const bf16x8*)(xsb + ((r * 256 + dd * 64 + lg * 16) ^ sw));
      }
      #pragma unroll
      for (int nf = 0; nf < 4; ++nf) {
        int r = wn * 64 + nf * 16 + lc;
        int sw = (r & 7) << 4;
        bfr[nf] = *(const bf16x8*)(wb + ((r * 256 + dd * 64 + lg * 16) ^ sw));
      }
      __builtin_amdgcn_s_setprio(1);
      #pragma unroll
      for (int mf = 0; mf < 2; ++mf)
        #pragma unroll
        for (int nf = 0; nf < 4; ++nf)
          acc[mf][nf] = __builtin_amdgcn_mfma_f32_16x16x32_bf16(a[mf], bfr[nf], acc[mf][nf], 0, 0, 0);
      __builtin_amdgcn_s_setprio(0);
    }
  }

  unsigned short* Ob = (wn == 0) ? Kb : Vb;
  #pragma unroll
  for (int mf = 0; mf < 2; ++mf)
    #pragma unroll
    for (int r = 0; r < 4; ++r) {
      int rg = row0 + wm * 32 + mf * 16 + lg * 4 + r;
      #pragma unroll
      for (int nf = 0; nf < 4; ++nf)
        Ob[(size_t)rg * HD + nf * 16 + lc] = f2bf(acc[mf][nf][r]);
    }
}

// ---------------- split-K flash attention, swapped QK^T, 32x32 MFMA ----------------
// 8 waves x 32 q = 256-q panel; 64-key iterations; chunk = 256/cperq keys.
// cperq selected at runtime from ws_size (1 -> 544 blocks, 2 -> 1088 blocks).
// Zero-work waves (chunk fully beyond diagonal) write l=0 partials (guarded).
__global__ __launch_bounds__(512) void attn_part(
    const unsigned short* __restrict__ Kb, const unsigned short* __restrict__ Vb,
    unsigned short* __restrict__ Opart, float* __restrict__ Ml, int cperq) {
  __shared__ __align__(16) unsigned char lds[32768];

  const int tid = threadIdx.x;
  const int lane = tid & 63;
  const int wq = tid >> 6;          // 0..7
  const int hi = lane >> 5;
  const int lq = lane & 31;

  const int b = blockIdx.x & 3;
  int qb = 0, c = 0;
  {
    int u = blockIdx.x >> 2, acc = 0;
    for (int q = 15; q >= 0; --q) {      // heavy (qb=15) panels first
      int nch = (q + 1) * cperq;
      if (u < acc + nch) { qb = q; c = u - acc; break; }
      acc += nch;
    }
  }
  const int nit = 4 / cperq;             // 64-key iterations per chunk
  const int kstart = c * (nit * 64);
  const int q0g = qb * 256 + wq * 32;
  const int qg = q0g + lq;
  const size_t base = (size_t)b * T_SEQ;
  const float SCALE2 = 0.18033688011112042f;     // 0.125 * log2(e)

  // Q B-fragments (Q == K rows), pre-scaled by SCALE2
  bf16x8 qf[4];
  {
    const unsigned short* qp = &Kb[(base + q0g + lq) * HD];
    #pragma unroll
    for (int dd = 0; dd < 4; ++dd) {
      bf16x8 t = *(const bf16x8*)&qp[dd * 16 + hi * 8];
      const unsigned short* ts = (const unsigned short*)&t;
      unsigned ow[4];
      #pragma unroll
      for (int w = 0; w < 4; ++w)
        ow[w] = cvt_pk_bf16(bf2f(ts[2 * w]) * SCALE2, bf2f(ts[2 * w + 1]) * SCALE2);
      u32x4v ov = {ow[0], ow[1], ow[2], ow[3]};
      qf[dd] = __builtin_bit_cast(bf16x8, ov);
    }
  }

  f32x16 oT0, oT1;
  #pragma unroll
  for (int r = 0; r < 16; ++r) { oT0[r] = 0.f; oT1[r] = 0.f; }
  float mreg = -1e30f, lreg = 0.f;               // m in log2 domain

  uint4 vreg0, vreg1;
  // K async stage: 512 chunks of 16B, one per thread.
  auto gload_K = [&](int jj, int buf) {
    const size_t kv0 = (base + kstart + (size_t)jj * 64) * HD;
    unsigned char* kb = lds + buf * 16384;
    int r = tid >> 3;
    int c8 = (tid & 7) ^ (r & 7);
    gload_lds16(&Kb[kv0 + (size_t)r * HD + c8 * 8], kb + wq * 1024);
  };
  // V staged by waves 0-3 (256 threads), 2 keys x 8 d per thread
  auto load_v = [&](int jj) {
    if (tid < 256) {
      const size_t kv0 = (base + kstart + (size_t)jj * 64) * HD;
      int key0 = (tid & 31) * 2, d0 = (tid >> 5) * 8;
      vreg0 = *(const uint4*)&Vb[kv0 + (size_t)key0 * HD + d0];
      vreg1 = *(const uint4*)&Vb[kv0 + (size_t)(key0 + 1) * HD + d0];
    }
  };
  auto write_v = [&](int buf) {
    if (tid < 256) {
      unsigned char* vb = lds + buf * 16384 + 8192;
      int key0 = (tid & 31) * 2, d0 = (tid >> 5) * 8;
      const unsigned short* pa = (const unsigned short*)&vreg0;
      const unsigned short* pb = (const unsigned short*)&vreg1;
      #pragma unroll
      for (int j = 0; j < 8; ++j) {
        unsigned val = (unsigned)pa[j] | ((unsigned)pb[j] << 16);
        int d = d0 + j;
        int byt = (d * 128 + key0 * 2) ^ ((d & 7) << 4);
        *(unsigned*)(vb + byt) = val;
      }
    }
  };

  auto qk = [&](int buf, int ksub) -> f32x16 {
    const unsigned char* kb = lds + buf * 16384;
    f32x16 sacc;
    #pragma unroll
    for (int r = 0; r < 16; ++r) sacc[r] = 0.f;
    const int krow = ksub * 32 + lq;
    const int ksw = (krow & 7) << 4;
    #pragma unroll
    for (int dd = 0; dd < 4; ++dd) {
      bf16x8 kf = *(const bf16x8*)(kb + ((krow * 128 + dd * 32 + hi * 16) ^ ksw));
      sacc = __builtin_amdgcn_mfma_f32_32x32x16_bf16(kf, qf[dd], sacc, 0, 0, 0);
    }
    return sacc;
  };
  auto maskdiag = [&](f32x16& s, int kbase_s) {
    #pragma unroll
    for (int r = 0; r < 16; ++r) {
      int key = kbase_s + (r & 3) + 8 * (r >> 2) + 4 * hi;
      if (key > qg) s[r] = -1e38f;
    }
  };
  auto max16 = [&](const f32x16& s) -> float {
    return fmaxf(
        fmaxf(fmaxf(fmaxf(s[0], s[1]), fmaxf(s[2], s[3])),
              fmaxf(fmaxf(s[4], s[5]), fmaxf(s[6], s[7]))),
        fmaxf(fmaxf(fmaxf(s[8], s[9]), fmaxf(s[10], s[11])),
              fmaxf(fmaxf(s[12], s[13]), fmaxf(s[14], s[15]))));
  };
  auto pack2 = [&](const f32x16& s, bf16x8& p1, bf16x8& p2) {
    unsigned pk[8];
    #pragma unroll
    for (int i = 0; i < 8; ++i) pk[i] = cvt_pk_bf16(s[2 * i], s[2 * i + 1]);
    unsigned wA[4], wB[4];
    #pragma unroll
    for (int i = 0; i < 2; ++i) {
      unsigned a0 = pk[i], b0 = pk[2 + i];
      unsigned sa = (unsigned)__shfl_xor((int)a0, 32);
      unsigned sb = (unsigned)__shfl_xor((int)b0, 32);
      wA[i] = hi ? sb : a0;
      wA[2 + i] = hi ? b0 : sa;
      unsigned c0 = pk[4 + i], d0v = pk[6 + i];
      unsigned sc = (unsigned)__shfl_xor((int)c0, 32);
      unsigned sd = (unsigned)__shfl_xor((int)d0v, 32);
      wB[i] = hi ? sd : c0;
      wB[2 + i] = hi ? d0v : sc;
    }
    u32x4v t1v = {wA[0], wA[1], wA[2], wA[3]};
    u32x4v t2v = {wB[0], wB[1], wB[2], wB[3]};
    p1 = __builtin_bit_cast(bf16x8, t1v);
    p2 = __builtin_bit_cast(bf16x8, t2v);
  };
  auto pv = [&](int buf, int ksub, bf16x8 pb1, bf16x8 pb2) {
    const unsigned char* vb = lds + buf * 16384 + 8192;
    const int cb = ksub * 64;
    {
      int drow = lq;
      int swz = (drow & 7) << 4;
      bf16x8 v0 = *(const bf16x8*)(vb + ((drow * 128 + cb + hi * 16) ^ swz));
      bf16x8 v1 = *(const bf16x8*)(vb + ((drow * 128 + cb + 32 + hi * 16) ^ swz));
      oT0 = __builtin_amdgcn_mfma_f32_32x32x16_bf16(v0, pb1, oT0, 0, 0, 0);
      oT0 = __builtin_amdgcn_mfma_f32_32x32x16_bf16(v1, pb2, oT0, 0, 0, 0);
    }
    {
      int drow = 32 + lq;
      int swz = (drow & 7) << 4;
      bf16x8 v0 = *(const bf16x8*)(vb + ((drow * 128 + cb + hi * 16) ^ swz));
      bf16x8 v1 = *(const bf16x8*)(vb + ((drow * 128 + cb + 32 + hi * 16) ^ swz));
      oT1 = __builtin_amdgcn_mfma_f32_32x32x16_bf16(v0, pb1, oT1, 0, 0, 0);
      oT1 = __builtin_amdgcn_mfma_f32_32x32x16_bf16(v1, pb2, oT1, 0, 0, 0);
    }
  };

  gload_K(0, 0);
  load_v(0);
  write_v(0);
  for (int jj = 0; jj < nit; ++jj) {
    const int cur = jj & 1;
    __syncthreads();                     // buf[cur] K(gload)+V(ds_write) ready
    if (jj + 1 < nit) { gload_K(jj + 1, cur ^ 1); load_v(jj + 1); }
    const int kb0 = kstart + jj * 64;

    if (kb0 + 32 <= q0g) {
      // ---- pair path: both subtiles, joint softmax ----
      __builtin_amdgcn_s_setprio(1);
      f32x16 s0 = qk(cur, 0);
      f32x16 s1 = qk(cur, 1);
      __builtin_amdgcn_s_setprio(0);
      if (kb0 + 32 == q0g) maskdiag(s1, kb0 + 32);
      float mx = fmaxf(max16(s0), max16(s1));
      mx = fmaxf(mx, __shfl_xor(mx, 32));
      if (!__all(mx <= mreg + 11.5f)) {
        float mn = fmaxf(mreg, mx);
        float al = exp2fast(mreg - mn);
        lreg *= al;
        #pragma unroll
        for (int r = 0; r < 16; ++r) { oT0[r] *= al; oT1[r] *= al; }
        mreg = mn;
      }
      float ps = 0.f;
      #pragma unroll
      for (int r = 0; r < 16; ++r) {
        float p0 = exp2fast(s0[r] - mreg);
        float p1 = exp2fast(s1[r] - mreg);
        ps += p0 + p1;
        s0[r] = p0;
        s1[r] = p1;
      }
      lreg += ps + __shfl_xor(ps, 32);
      bf16x8 pa1, pa2, pbb1, pbb2;
      pack2(s0, pa1, pa2);
      pack2(s1, pbb1, pbb2);
      __builtin_amdgcn_s_setprio(1);
      pv(cur, 0, pa1, pa2);
      pv(cur, 1, pbb1, pbb2);
      __builtin_amdgcn_s_setprio(0);
    } else if (kb0 <= q0g) {
      // ---- single path: sub0 only (possibly diagonal) ----
      __builtin_amdgcn_s_setprio(1);
      f32x16 s0 = qk(cur, 0);
      __builtin_amdgcn_s_setprio(0);
      if (kb0 == q0g) maskdiag(s0, kb0);
      float mx = max16(s0);
      mx = fmaxf(mx, __shfl_xor(mx, 32));
      if (!__all(mx <= mreg + 11.5f)) {
        float mn = fmaxf(mreg, mx);
        float al = exp2fast(mreg - mn);
        lreg *= al;
        #pragma unroll
        for (int r = 0; r < 16; ++r) { oT0[r] *= al; oT1[r] *= al; }
        mreg = mn;
      }
      float ps = 0.f;
      #pragma unroll
      for (int r = 0; r < 16; ++r) {
        float p = exp2fast(s0[r] - mreg);
        ps += p;
        s0[r] = p;
      }
      lreg += ps + __shfl_xor(ps, 32);
      bf16x8 pa1, pa2;
      pack2(s0, pa1, pa2);
      __builtin_amdgcn_s_setprio(1);
      pv(cur, 0, pa1, pa2);
      __builtin_amdgcn_s_setprio(0);
    }

    if (jj + 1 < nit) write_v(cur ^ 1);  // vmcnt wait (V loads) lands post-compute
  }

  // ---- write normalized bf16 partial [256 q][64 d] + (m2, l) ----
  // GUARD: zero-work waves (lreg==0) write zeros; merge weight exp2(m-M)*l = 0.
  unsigned short* op = Opart + (size_t)blockIdx.x * 16384;
  float* mlp = Ml + (size_t)blockIdx.x * 512;
  const float invl = (lreg > 0.f) ? (1.0f / lreg) : 0.f;
  const int qrow = wq * 32 + lq;
  #pragma unroll
  for (int g = 0; g < 4; ++g) {
    int d0 = 8 * g + 4 * hi;
    uint2 w0, w1;
    w0.x = cvt_pk_bf16(oT0[4 * g] * invl, oT0[4 * g + 1] * invl);
    w0.y = cvt_pk_bf16(oT0[4 * g + 2] * invl, oT0[4 * g + 3] * invl);
    w1.x = cvt_pk_bf16(oT1[4 * g] * invl, oT1[4 * g + 1] * invl);
    w1.y = cvt_pk_bf16(oT1[4 * g + 2] * invl, oT1[4 * g + 3] * invl);
    *(uint2*)&op[qrow * 64 + d0] = w0;
    *(uint2*)&op[qrow * 64 + d0 + 32] = w1;
  }
  if (hi == 0) {
    mlp[qrow * 2] = mreg;
    mlp[qrow * 2 + 1] = lreg;
  }
}

// ---------------- phase 2: merge panel partials (8 d per thread, uint4 loads) ----------------
__global__ __launch_bounds__(256) void attn_merge(
    const unsigned short* __restrict__ Opart, const float* __restrict__ Ml,
    float* __restrict__ out, int cperq) {
  int g = blockIdx.x * 256 + threadIdx.x;   // 131072 total
  int d8 = (g & 7) * 8;
  int row = g >> 3;              // 0..16383
  int b = row >> 12;
  int t = row & (T_SEQ - 1);
  int qp = t >> 8;               // 0..15
  int r256 = t & 255;
  int nch = (qp + 1) * cperq;
  int us = 0;
  for (int q = 15; q > qp; --q) us += (q + 1) * cperq;
  float M = -1e30f;
  for (int cc = 0; cc < nch; ++cc) {
    int part = (us + cc) * 4 + b;
    M = fmaxf(M, Ml[(size_t)part * 512 + r256 * 2]);
  }
  float L = 0.f;
  float o[8];
  #pragma unroll
  for (int j = 0; j < 8; ++j) o[j] = 0.f;
  for (int cc = 0; cc < nch; ++cc) {
    int part = (us + cc) * 4 + b;
    float mc = Ml[(size_t)part * 512 + r256 * 2];
    float lc = Ml[(size_t)part * 512 + r256 * 2 + 1];
    if (lc <= 0.f) continue;            // zero-work chunk: no contribution
    float w = exp2fast(mc - M) * lc;
    L += w;
    uint4 v = *(const uint4*)&Opart[(size_t)part * 16384 + r256 * 64 + d8];
    const unsigned short* pv = (const unsigned short*)&v;
    #pragma unroll
    for (int j = 0; j < 8; ++j) o[j] += w * bf2f(pv[j]);
  }
  float inv = 1.0f / L;
  size_t og = ((size_t)b * T_SEQ + qp * 256 + r256) * 64 + d8;
  float4 r0 = make_float4(o[0] * inv, o[1] * inv, o[2] * inv, o[3] * inv);
  float4 r1 = make_float4(o[4] * inv, o[5] * inv, o[6] * inv, o[7] * inv);
  *(float4*)&out[og] = r0;
  *(float4*)&out[og + 4] = r1;
}

extern "C" void kernel_launch(void* const* d_in, const int* in_sizes, int n_in,
                              void* d_out, int out_size, void* d_ws, size_t ws_size,
                              hipStream_t stream) {
  const float* x  = (const float*)d_in[0];
  const float* Wk = (const float*)d_in[1];
  const float* Wv = (const float*)d_in[2];
  unsigned short* Kb = (unsigned short*)d_ws;                 // 2 MB
  unsigned short* Vb = Kb + (size_t)NROWS * HD;               // 2 MB
  unsigned short* Wt = Vb + (size_t)NROWS * HD;               // 256 KB
  unsigned short* Opart = Wt + (size_t)128 * CDIM;

  // runtime split-K factor: finer split (1088 blocks) iff workspace allows
  const size_t fixed = (size_t)(2 * NROWS * HD) * 2 + (size_t)128 * CDIM * 2;  // Kb+Vb+Wt bytes
  int cperq = 1;
  {
    size_t need2 = fixed + (size_t)1088 * 16384 * 2 + (size_t)1088 * 512 * 4;
    if (ws_size >= need2) cperq = 2;
  }
  const int nblocks = 544 * cperq;
  float* Ml = (float*)(Opart + (size_t)nblocks * 16384);
  float* o = (float*)d_out;

  prep_w<<<32, 256, 0, stream>>>(Wk, Wv, Wt);
  proj_mfma<<<256, 256, 0, stream>>>(x, Wt, Kb, Vb);
  attn_part<<<nblocks, 512, 0, stream>>>(Kb, Vb, Opart, Ml, cperq);
  attn_merge<<<512, 256, 0, stream>>>(Opart, Ml, o, cperq);
}

// Round 29
// 70.204 us; speedup vs baseline: 1.3217x; 1.3217x over previous
//
#include <hip/hip_runtime.h>

typedef short bf16x8 __attribute__((ext_vector_type(8)));
typedef float f32x4 __attribute__((ext_vector_type(4)));
typedef float f32x16 __attribute__((ext_vector_type(16)));
typedef unsigned u32x4v __attribute__((ext_vector_type(4)));

#define T_SEQ 4096
#define CDIM  1024
#define HD    64
#define NROWS 16384  // B*T

__device__ inline float exp2fast(float x) {
  return __builtin_amdgcn_exp2f(x);   // v_exp_f32: D = 2^S0
}

__device__ inline unsigned short f2bf(float f) {
  unsigned u = __builtin_bit_cast(unsigned, f);
  u = (u + 0x7fffu + ((u >> 16) & 1u)) >> 16;
  return (unsigned short)u;
}
__device__ inline unsigned cvt_pk_bf16(float lo, float hi) {
  unsigned r;
  asm("v_cvt_pk_bf16_f32 %0, %1, %2" : "=v"(r) : "v"(lo), "v"(hi));
  return r;
}
__device__ inline float bf2f(unsigned short u) {
  unsigned v = (unsigned)u << 16;
  return __builtin_bit_cast(float, v);
}
// async global->LDS, 16B per lane; LDS dest = wave-uniform base + lane*16
__device__ inline void gload_lds16(const unsigned short* g, unsigned char* l) {
  __builtin_amdgcn_global_load_lds(
      (const __attribute__((address_space(1))) unsigned int*)(const void*)g,
      (__attribute__((address_space(3))) unsigned int*)(void*)l, 16, 0, 0);
}

// ---------------- W prep (LDS transpose): Wt[n][k] bf16 ----------------
__global__ __launch_bounds__(256) void prep_w(
    const float* __restrict__ Wk, const float* __restrict__ Wv,
    unsigned short* __restrict__ Wt) {
  __shared__ float tile[64][68];
  const int t = threadIdx.x;
  const int mat = blockIdx.x & 1;
  const int k0 = (blockIdx.x >> 1) * 64;
  const float* W = mat ? Wv : Wk;
  #pragma unroll
  for (int pp = 0; pp < 4; ++pp) {
    int idx = t + 256 * pp, row = idx >> 4, c4 = idx & 15;
    float4 v = *(const float4*)&W[(size_t)(k0 + row) * HD + c4 * 4];
    *(float4*)&tile[row][c4 * 4] = v;
  }
  __syncthreads();
  #pragma unroll
  for (int j = 0; j < 2; ++j) {
    int n = t & 63, j8 = (t >> 6) + 4 * j;
    unsigned ow[4];
    #pragma unroll
    for (int w = 0; w < 4; ++w)
      ow[w] = cvt_pk_bf16(tile[j8 * 8 + 2 * w][n], tile[j8 * 8 + 2 * w + 1][n]);
    u32x4v ov = {ow[0], ow[1], ow[2], ow[3]};
    *(u32x4v*)&Wt[(size_t)(mat * 64 + n) * CDIM + k0 + j8 * 8] = ov;
  }
}

// ---------------- projection GEMM: [K|V] = x @ Wt^T, bf16 MFMA ----------------
// (verified rounds 24-26)
__global__ __launch_bounds__(256) void proj_mfma(
    const float* __restrict__ x, const unsigned short* __restrict__ Wt,
    unsigned short* __restrict__ Kb, unsigned short* __restrict__ Vb) {
  __shared__ __align__(16) unsigned char xsb[16384];
  __shared__ __align__(16) unsigned char wsb[65536];
  const int tid = threadIdx.x;
  const int lane = tid & 63, wave = tid >> 6;
  const int wm = wave & 1, wn = wave >> 1;
  const int lg = lane >> 4, lc = lane & 15;
  const int row0 = blockIdx.x * 64;

  float4 xreg[8];
  auto load_x = [&](int kk) {
    #pragma unroll
    for (int p = 0; p < 8; ++p) {
      int idx = tid + 256 * p, r = idx >> 5, c4 = idx & 31;
      xreg[p] = *(const float4*)&x[(size_t)(row0 + r) * CDIM + kk + c4 * 4];
    }
  };
  auto write_x = [&]() {
    #pragma unroll
    for (int p = 0; p < 8; ++p) {
      int idx = tid + 256 * p, r = idx >> 5, c4 = idx & 31;
      uint2 v;
      v.x = cvt_pk_bf16(xreg[p].x, xreg[p].y);
      v.y = cvt_pk_bf16(xreg[p].z, xreg[p].w);
      int byt = (r * 256 + c4 * 8) ^ ((r & 7) << 4);
      *(uint2*)(xsb + byt) = v;
    }
  };
  auto gload_W = [&](int kk, int buf) {
    unsigned char* wb = wsb + buf * 32768;
    #pragma unroll
    for (int p = 0; p < 8; ++p) {
      int ci = p * 256 + tid;
      int r = ci >> 4;
      int c8 = (ci & 15) ^ (r & 7);
      gload_lds16(&Wt[(size_t)r * CDIM + kk + c8 * 8],
                  wb + (p * 256 + wave * 64) * 16);
    }
  };

  f32x4 acc[2][4];
  #pragma unroll
  for (int mf = 0; mf < 2; ++mf)
    #pragma unroll
    for (int nf = 0; nf < 4; ++nf) acc[mf][nf] = (f32x4){0.f, 0.f, 0.f, 0.f};

  gload_W(0, 0);
  load_x(0);
  for (int kk = 0; kk < CDIM; kk += 128) {
    const int cur = (kk >> 7) & 1;
    __syncthreads();
    write_x();
    __syncthreads();
    if (kk + 128 < CDIM) { gload_W(kk + 128, cur ^ 1); load_x(kk + 128); }
    const unsigned char* wb = wsb + cur * 32768;
    #pragma unroll
    for (int dd = 0; dd < 4; ++dd) {
      bf16x8 a[2], bfr[4];
      #pragma unroll
      for (int mf = 0; mf < 2; ++mf) {
        int r = wm * 32 + mf * 16 + lc;
        int sw = (r & 7) << 4;
        a[mf] = *(const bf16x8*)(xsb + ((r * 256 + dd * 64 + lg * 16) ^ sw));
      }
      #pragma unroll
      for (int nf = 0; nf < 4; ++nf) {
        int r = wn * 64 + nf * 16 + lc;
        int sw = (r & 7) << 4;
        bfr[nf] = *(const bf16x8*)(wb + ((r * 256 + dd * 64 + lg * 16) ^ sw));
      }
      __builtin_amdgcn_s_setprio(1);
      #pragma unroll
      for (int mf = 0; mf < 2; ++mf)
        #pragma unroll
        for (int nf = 0; nf < 4; ++nf)
          acc[mf][nf] = __builtin_amdgcn_mfma_f32_16x16x32_bf16(a[mf], bfr[nf], acc[mf][nf], 0, 0, 0);
      __builtin_amdgcn_s_setprio(0);
    }
  }

  unsigned short* Ob = (wn == 0) ? Kb : Vb;
  #pragma unroll
  for (int mf = 0; mf < 2; ++mf)
    #pragma unroll
    for (int r = 0; r < 4; ++r) {
      int rg = row0 + wm * 32 + mf * 16 + lg * 4 + r;
      #pragma unroll
      for (int nf = 0; nf < 4; ++nf)
        Ob[(size_t)rg * HD + nf * 16 + lc] = f2bf(acc[mf][nf][r]);
    }
}

// ---------------- split-K flash attention, swapped QK^T, 32x32 MFMA ----------------
// (verified round 26 — best config, 70.3 us total)
// 8 waves x 32 q = 256-q panel; 128-key iterations (nit=2/chunk).
// LDS 64KB: 2 bufs x (K[128x64] 16KB + V^T[64][128] 16KB). 544 blocks x 512 thr.
__global__ __launch_bounds__(512) void attn_part(
    const unsigned short* __restrict__ Kb, const unsigned short* __restrict__ Vb,
    unsigned short* __restrict__ Opart, float* __restrict__ Ml) {
  __shared__ __align__(16) unsigned char lds[65536];

  const int tid = threadIdx.x;
  const int lane = tid & 63;
  const int wq = tid >> 6;          // 0..7
  const int hi = lane >> 5;
  const int lq = lane & 31;

  const int b = blockIdx.x & 3;
  int qb = 0, c = 0;
  {
    int u = blockIdx.x >> 2, acc = 0;
    for (int q = 15; q >= 0; --q) {      // heavy (qb=15) panels first
      int nch = q + 1;                   // (qb+1)*256 keys / 256-key chunks
      if (u < acc + nch) { qb = q; c = u - acc; break; }
      acc += nch;
    }
  }
  const int kstart = c * 256;            // always full 256-key chunk; 2 iters x 128 keys
  const int q0g = qb * 256 + wq * 32;
  const int qg = q0g + lq;
  const size_t base = (size_t)b * T_SEQ;
  const float SCALE2 = 0.18033688011112042f;     // 0.125 * log2(e)

  // Q B-fragments (Q == K rows), pre-scaled by SCALE2
  bf16x8 qf[4];
  {
    const unsigned short* qp = &Kb[(base + q0g + lq) * HD];
    #pragma unroll
    for (int dd = 0; dd < 4; ++dd) {
      bf16x8 t = *(const bf16x8*)&qp[dd * 16 + hi * 8];
      const unsigned short* ts = (const unsigned short*)&t;
      unsigned ow[4];
      #pragma unroll
      for (int w = 0; w < 4; ++w)
        ow[w] = cvt_pk_bf16(bf2f(ts[2 * w]) * SCALE2, bf2f(ts[2 * w + 1]) * SCALE2);
      u32x4v ov = {ow[0], ow[1], ow[2], ow[3]};
      qf[dd] = __builtin_bit_cast(bf16x8, ov);
    }
  }

  f32x16 oT0, oT1;
  #pragma unroll
  for (int r = 0; r < 16; ++r) { oT0[r] = 0.f; oT1[r] = 0.f; }
  float mreg = -1e30f, lreg = 0.f;               // m in log2 domain

  uint4 vreg0, vreg1;
  // K async stage: 1024 chunks of 16B (128 keys x 128B), 2 per thread.
  auto gload_K = [&](int jj, int buf) {
    const size_t kv0 = (base + kstart + (size_t)jj * 128) * HD;
    unsigned char* kb = lds + buf * 32768;
    #pragma unroll
    for (int p = 0; p < 2; ++p) {
      int ci = p * 512 + tid;
      int r = ci >> 3;
      int c8 = (ci & 7) ^ (r & 7);
      gload_lds16(&Kb[kv0 + (size_t)r * HD + c8 * 8],
                  kb + (p * 512 + wq * 64) * 16);
    }
  };
  // V staged by all 8 waves: 2 keys x 8 d per thread (128 keys x 64 d)
  auto load_v = [&](int jj) {
    const size_t kv0 = (base + kstart + (size_t)jj * 128) * HD;
    int key0 = (tid & 63) * 2, d0 = (tid >> 6) * 8;
    vreg0 = *(const uint4*)&Vb[kv0 + (size_t)key0 * HD + d0];
    vreg1 = *(const uint4*)&Vb[kv0 + (size_t)(key0 + 1) * HD + d0];
  };
  auto write_v = [&](int buf) {
    unsigned char* vb = lds + buf * 32768 + 16384;
    int key0 = (tid & 63) * 2, d0 = (tid >> 6) * 8;
    const unsigned short* pa = (const unsigned short*)&vreg0;
    const unsigned short* pb = (const unsigned short*)&vreg1;
    #pragma unroll
    for (int j = 0; j < 8; ++j) {
      unsigned val = (unsigned)pa[j] | ((unsigned)pb[j] << 16);
      int d = d0 + j;
      int byt = (d * 256 + key0 * 2) ^ ((d & 7) << 4);
      *(unsigned*)(vb + byt) = val;
    }
  };

  auto qk = [&](int buf, int ksub) -> f32x16 {
    const unsigned char* kb = lds + buf * 32768;
    f32x16 sacc;
    #pragma unroll
    for (int r = 0; r < 16; ++r) sacc[r] = 0.f;
    const int krow = ksub * 32 + lq;
    const int ksw = (krow & 7) << 4;
    #pragma unroll
    for (int dd = 0; dd < 4; ++dd) {
      bf16x8 kf = *(const bf16x8*)(kb + ((krow * 128 + dd * 32 + hi * 16) ^ ksw));
      sacc = __builtin_amdgcn_mfma_f32_32x32x16_bf16(kf, qf[dd], sacc, 0, 0, 0);
    }
    return sacc;
  };
  auto maskdiag = [&](f32x16& s, int kbase_s) {
    #pragma unroll
    for (int r = 0; r < 16; ++r) {
      int key = kbase_s + (r & 3) + 8 * (r >> 2) + 4 * hi;
      if (key > qg) s[r] = -1e38f;
    }
  };
  auto max16 = [&](const f32x16& s) -> float {
    return fmaxf(
        fmaxf(fmaxf(fmaxf(s[0], s[1]), fmaxf(s[2], s[3])),
              fmaxf(fmaxf(s[4], s[5]), fmaxf(s[6], s[7]))),
        fmaxf(fmaxf(fmaxf(s[8], s[9]), fmaxf(s[10], s[11])),
              fmaxf(fmaxf(s[12], s[13]), fmaxf(s[14], s[15]))));
  };
  auto pack2 = [&](const f32x16& s, bf16x8& p1, bf16x8& p2) {
    unsigned pk[8];
    #pragma unroll
    for (int i = 0; i < 8; ++i) pk[i] = cvt_pk_bf16(s[2 * i], s[2 * i + 1]);
    unsigned wA[4], wB[4];
    #pragma unroll
    for (int i = 0; i < 2; ++i) {
      unsigned a0 = pk[i], b0 = pk[2 + i];
      unsigned sa = (unsigned)__shfl_xor((int)a0, 32);
      unsigned sb = (unsigned)__shfl_xor((int)b0, 32);
      wA[i] = hi ? sb : a0;
      wA[2 + i] = hi ? b0 : sa;
      unsigned c0 = pk[4 + i], d0v = pk[6 + i];
      unsigned sc = (unsigned)__shfl_xor((int)c0, 32);
      unsigned sd = (unsigned)__shfl_xor((int)d0v, 32);
      wB[i] = hi ? sd : c0;
      wB[2 + i] = hi ? d0v : sc;
    }
    u32x4v t1v = {wA[0], wA[1], wA[2], wA[3]};
    u32x4v t2v = {wB[0], wB[1], wB[2], wB[3]};
    p1 = __builtin_bit_cast(bf16x8, t1v);
    p2 = __builtin_bit_cast(bf16x8, t2v);
  };
  auto pv = [&](int buf, int ksub, bf16x8 pb1, bf16x8 pb2) {
    const unsigned char* vb = lds + buf * 32768 + 16384;
    const int cb = ksub * 64;
    {
      int drow = lq;
      int swz = (drow & 7) << 4;
      bf16x8 v0 = *(const bf16x8*)(vb + ((drow * 256 + cb + hi * 16) ^ swz));
      bf16x8 v1 = *(const bf16x8*)(vb + ((drow * 256 + cb + 32 + hi * 16) ^ swz));
      oT0 = __builtin_amdgcn_mfma_f32_32x32x16_bf16(v0, pb1, oT0, 0, 0, 0);
      oT0 = __builtin_amdgcn_mfma_f32_32x32x16_bf16(v1, pb2, oT0, 0, 0, 0);
    }
    {
      int drow = 32 + lq;
      int swz = (drow & 7) << 4;
      bf16x8 v0 = *(const bf16x8*)(vb + ((drow * 256 + cb + hi * 16) ^ swz));
      bf16x8 v1 = *(const bf16x8*)(vb + ((drow * 256 + cb + 32 + hi * 16) ^ swz));
      oT1 = __builtin_amdgcn_mfma_f32_32x32x16_bf16(v0, pb1, oT1, 0, 0, 0);
      oT1 = __builtin_amdgcn_mfma_f32_32x32x16_bf16(v1, pb2, oT1, 0, 0, 0);
    }
  };

  gload_K(0, 0);
  load_v(0);
  write_v(0);
  for (int jj = 0; jj < 2; ++jj) {
    const int cur = jj & 1;
    __syncthreads();                     // buf[cur] K(gload)+V(ds_write) ready
    if (jj == 0) { gload_K(1, 1); load_v(1); }

    #pragma unroll
    for (int h = 0; h < 2; ++h) {
      const int kb0 = kstart + jj * 128 + h * 64;
      const int su = h * 2;              // subtile index pair: su, su+1

      if (kb0 + 32 <= q0g) {
        // ---- pair path: both subtiles, joint softmax ----
        __builtin_amdgcn_s_setprio(1);
        f32x16 s0 = qk(cur, su);
        f32x16 s1 = qk(cur, su + 1);
        __builtin_amdgcn_s_setprio(0);
        if (kb0 + 32 == q0g) maskdiag(s1, kb0 + 32);
        float mx = fmaxf(max16(s0), max16(s1));
        mx = fmaxf(mx, __shfl_xor(mx, 32));
        if (!__all(mx <= mreg + 11.5f)) {
          float mn = fmaxf(mreg, mx);
          float al = exp2fast(mreg - mn);
          lreg *= al;
          #pragma unroll
          for (int r = 0; r < 16; ++r) { oT0[r] *= al; oT1[r] *= al; }
          mreg = mn;
        }
        float ps = 0.f;
        #pragma unroll
        for (int r = 0; r < 16; ++r) {
          float p0 = exp2fast(s0[r] - mreg);
          float p1 = exp2fast(s1[r] - mreg);
          ps += p0 + p1;
          s0[r] = p0;
          s1[r] = p1;
        }
        lreg += ps + __shfl_xor(ps, 32);
        bf16x8 pa1, pa2, pbb1, pbb2;
        pack2(s0, pa1, pa2);
        pack2(s1, pbb1, pbb2);
        __builtin_amdgcn_s_setprio(1);
        pv(cur, su, pa1, pa2);
        pv(cur, su + 1, pbb1, pbb2);
        __builtin_amdgcn_s_setprio(0);
      } else if (kb0 <= q0g) {
        // ---- single path: first subtile only (possibly diagonal) ----
        __builtin_amdgcn_s_setprio(1);
        f32x16 s0 = qk(cur, su);
        __builtin_amdgcn_s_setprio(0);
        if (kb0 == q0g) maskdiag(s0, kb0);
        float mx = max16(s0);
        mx = fmaxf(mx, __shfl_xor(mx, 32));
        if (!__all(mx <= mreg + 11.5f)) {
          float mn = fmaxf(mreg, mx);
          float al = exp2fast(mreg - mn);
          lreg *= al;
          #pragma unroll
          for (int r = 0; r < 16; ++r) { oT0[r] *= al; oT1[r] *= al; }
          mreg = mn;
        }
        float ps = 0.f;
        #pragma unroll
        for (int r = 0; r < 16; ++r) {
          float p = exp2fast(s0[r] - mreg);
          ps += p;
          s0[r] = p;
        }
        lreg += ps + __shfl_xor(ps, 32);
        bf16x8 pa1, pa2;
        pack2(s0, pa1, pa2);
        __builtin_amdgcn_s_setprio(1);
        pv(cur, su, pa1, pa2);
        __builtin_amdgcn_s_setprio(0);
      }
    }

    if (jj == 0) write_v(1);             // vmcnt wait (V loads) lands post-compute
  }

  // ---- write normalized bf16 partial [256 q][64 d] + (m2, l) ----
  unsigned short* op = Opart + (size_t)blockIdx.x * 16384;
  float* mlp = Ml + (size_t)blockIdx.x * 512;
  const float invl = 1.0f / lreg;
  const int qrow = wq * 32 + lq;
  #pragma unroll
  for (int g = 0; g < 4; ++g) {
    int d0 = 8 * g + 4 * hi;
    uint2 w0, w1;
    w0.x = cvt_pk_bf16(oT0[4 * g] * invl, oT0[4 * g + 1] * invl);
    w0.y = cvt_pk_bf16(oT0[4 * g + 2] * invl, oT0[4 * g + 3] * invl);
    w1.x = cvt_pk_bf16(oT1[4 * g] * invl, oT1[4 * g + 1] * invl);
    w1.y = cvt_pk_bf16(oT1[4 * g + 2] * invl, oT1[4 * g + 3] * invl);
    *(uint2*)&op[qrow * 64 + d0] = w0;
    *(uint2*)&op[qrow * 64 + d0 + 32] = w1;
  }
  if (hi == 0) {
    mlp[qrow * 2] = mreg;
    mlp[qrow * 2 + 1] = lreg;
  }
}

// ---------------- phase 2: merge panel partials (8 d per thread, uint4 loads) ----------------
__global__ __launch_bounds__(256) void attn_merge(
    const unsigned short* __restrict__ Opart, const float* __restrict__ Ml,
    float* __restrict__ out) {
  int g = blockIdx.x * 256 + threadIdx.x;   // 131072 total
  int d8 = (g & 7) * 8;
  int row = g >> 3;              // 0..16383
  int b = row >> 12;
  int t = row & (T_SEQ - 1);
  int qp = t >> 8;               // 0..15
  int r256 = t & 255;
  int nch = qp + 1;
  int us = 0;
  for (int q = 15; q > qp; --q) us += q + 1;
  float M = -1e30f;
  for (int cc = 0; cc < nch; ++cc) {
    int part = (us + cc) * 4 + b;
    M = fmaxf(M, Ml[(size_t)part * 512 + r256 * 2]);
  }
  float L = 0.f;
  float o[8];
  #pragma unroll
  for (int j = 0; j < 8; ++j) o[j] = 0.f;
  for (int cc = 0; cc < nch; ++cc) {
    int part = (us + cc) * 4 + b;
    float mc = Ml[(size_t)part * 512 + r256 * 2];
    float lc = Ml[(size_t)part * 512 + r256 * 2 + 1];
    float w = exp2fast(mc - M) * lc;
    L += w;
    uint4 v = *(const uint4*)&Opart[(size_t)part * 16384 + r256 * 64 + d8];
    const unsigned short* pv = (const unsigned short*)&v;
    #pragma unroll
    for (int j = 0; j < 8; ++j) o[j] += w * bf2f(pv[j]);
  }
  float inv = 1.0f / L;
  size_t og = ((size_t)b * T_SEQ + qp * 256 + r256) * 64 + d8;
  float4 r0 = make_float4(o[0] * inv, o[1] * inv, o[2] * inv, o[3] * inv);
  float4 r1 = make_float4(o[4] * inv, o[5] * inv, o[6] * inv, o[7] * inv);
  *(float4*)&out[og] = r0;
  *(float4*)&out[og + 4] = r1;
}

extern "C" void kernel_launch(void* const* d_in, const int* in_sizes, int n_in,
                              void* d_out, int out_size, void* d_ws, size_t ws_size,
                              hipStream_t stream) {
  const float* x  = (const float*)d_in[0];
  const float* Wk = (const float*)d_in[1];
  const float* Wv = (const float*)d_in[2];
  unsigned short* Kb = (unsigned short*)d_ws;                 // 2 MB
  unsigned short* Vb = Kb + (size_t)NROWS * HD;               // 2 MB
  unsigned short* Wt = Vb + (size_t)NROWS * HD;               // 256 KB
  unsigned short* Opart = Wt + (size_t)128 * CDIM;            // 544 * 16384 * 2B = 17.8 MB
  float* Ml = (float*)(Opart + (size_t)544 * 16384);          // 544 * 512 * 4B = 1.1 MB
  float* o = (float*)d_out;

  prep_w<<<32, 256, 0, stream>>>(Wk, Wv, Wt);
  proj_mfma<<<256, 256, 0, stream>>>(x, Wt, Kb, Vb);
  attn_part<<<544, 512, 0, stream>>>(Kb, Vb, Opart, Ml);
  attn_merge<<<512, 256, 0, stream>>>(Opart, Ml, o);
}